// Round 4
// baseline (177.179 us; speedup 1.0000x reference)
//
#include <hip/hip_runtime.h>
#include <hip/hip_fp16.h>

// bias = (1/nnz) * sum_e vals[e] * dot(x[rows[e]], x[cols[e]])
// N_FEAT = 128.
//
// Round-4: feature-sliced gather. xf[k] = fp16 columns [16k,16k+16) of x,
// stored compact: [n_nodes][16] = 3.2MB -> resident in XCD k's 4MB L2.
// Block b (XCD b&7) processes slice b&7 for ALL edges; every gather is an
// L2 hit after first touch. Edge records packed to 8B (row|col|val_fp16),
// read nontemporally so the stream doesn't evict the slice.

union Pack32 { __half2 h2[8]; float4 f4[2]; };

// x [n][128] f32  ->  xf [8][n][16] f16
__global__ __launch_bounds__(256) void slice_f2h_kernel(
    const float* __restrict__ x, __half* __restrict__ xf, int n_nodes)
{
    int n = blockIdx.x * blockDim.x + threadIdx.x;
    const int stride = gridDim.x * blockDim.x;
    for (; n < n_nodes; n += stride) {
        const float4* xr = reinterpret_cast<const float4*>(x + (size_t)n * 128);
        #pragma unroll
        for (int k = 0; k < 8; ++k) {
            const float4 f0 = xr[k * 4 + 0];
            const float4 f1 = xr[k * 4 + 1];
            const float4 f2 = xr[k * 4 + 2];
            const float4 f3 = xr[k * 4 + 3];
            Pack32 p;
            p.h2[0] = __floats2half2_rn(f0.x, f0.y);
            p.h2[1] = __floats2half2_rn(f0.z, f0.w);
            p.h2[2] = __floats2half2_rn(f1.x, f1.y);
            p.h2[3] = __floats2half2_rn(f1.z, f1.w);
            p.h2[4] = __floats2half2_rn(f2.x, f2.y);
            p.h2[5] = __floats2half2_rn(f2.z, f2.w);
            p.h2[6] = __floats2half2_rn(f3.x, f3.y);
            p.h2[7] = __floats2half2_rn(f3.z, f3.w);
            float4* dst = reinterpret_cast<float4*>(
                xf + ((size_t)k * n_nodes + n) * 16);
            dst[0] = p.f4[0];
            dst[1] = p.f4[1];
        }
    }
}

// (row, col, val) -> 8B record: row[0:17) | col[17:34) | half(val)[34:50)
__global__ __launch_bounds__(256) void pack_edges_kernel(
    const int* __restrict__ rows, const int* __restrict__ cols,
    const float* __restrict__ vals,
    unsigned long long* __restrict__ packed, int nnz)
{
    int e = blockIdx.x * blockDim.x + threadIdx.x;
    const int stride = gridDim.x * blockDim.x;
    for (; e < nnz; e += stride) {
        const unsigned long long r = (unsigned)rows[e];
        const unsigned long long c = (unsigned)cols[e];
        const __half hv = __float2half_rn(vals[e]);
        const unsigned long long hb =
            (unsigned long long)*reinterpret_cast<const unsigned short*>(&hv);
        packed[e] = r | (c << 17) | (hb << 34);
    }
}

__device__ __forceinline__ float dot16_h(const float4& af, const float4& bf)
{
    const __half2* a2 = reinterpret_cast<const __half2*>(&af);
    const __half2* b2 = reinterpret_cast<const __half2*>(&bf);
    float d = 0.0f;
    #pragma unroll
    for (int k = 0; k < 4; ++k) {
        const float2 fa = __half22float2(a2[k]);
        const float2 fb = __half22float2(b2[k]);
        d += fa.x * fb.x + fa.y * fb.y;
    }
    return d;
}

__device__ __forceinline__ void block_reduce_store(
    float acc, float* __restrict__ partials)
{
    #pragma unroll
    for (int m = 1; m < 64; m <<= 1)
        acc += __shfl_xor(acc, m);
    __shared__ float s_red[4];
    const int lane = threadIdx.x & 63;
    const int wid  = threadIdx.x >> 6;
    if (lane == 0) s_red[wid] = acc;
    __syncthreads();
    if (threadIdx.x == 0)
        partials[blockIdx.x] = s_red[0] + s_red[1] + s_red[2] + s_red[3];
}

// main gather: 2 lanes per edge, each lane does 16B of row + 16B of col
__global__ __launch_bounds__(256) void edge_dot_slice_packed(
    const __half* __restrict__ xf,
    const unsigned long long* __restrict__ packed,
    float* __restrict__ partials, int nnz, int n_nodes)
{
    const int oct  = blockIdx.x & 7;     // XCD / feature-slice id
    const int obid = blockIdx.x >> 3;
    const int nb   = gridDim.x >> 3;
    const float4* __restrict__ slice =
        reinterpret_cast<const float4*>(xf) + (size_t)oct * n_nodes * 2;

    const int j  = threadIdx.x & 1;      // which 16B half of the 32B slice-row
    const int pr = threadIdx.x >> 1;     // pair index within block

    float acc = 0.0f;
    const long long estep = (long long)nb * 128;
    long long e = (long long)obid * 128 + pr;
    #pragma unroll 2
    for (; e < nnz; e += estep) {
        const unsigned long long u = __builtin_nontemporal_load(packed + e);
        const int r = (int)(u & 0x1FFFF);
        const int c = (int)((u >> 17) & 0x1FFFF);
        const unsigned short hb = (unsigned short)(u >> 34);
        const float v = __half2float(*reinterpret_cast<const __half*>(&hb));
        const float4 af = slice[(size_t)r * 2 + j];
        const float4 bf = slice[(size_t)c * 2 + j];
        acc += v * dot16_h(af, bf);
    }
    block_reduce_store(acc, partials);
}

// variant without the packed array (smaller workspace): reads raw edge lists
__global__ __launch_bounds__(256) void edge_dot_slice_raw(
    const __half* __restrict__ xf,
    const int* __restrict__ rows, const int* __restrict__ cols,
    const float* __restrict__ vals,
    float* __restrict__ partials, int nnz, int n_nodes)
{
    const int oct  = blockIdx.x & 7;
    const int obid = blockIdx.x >> 3;
    const int nb   = gridDim.x >> 3;
    const float4* __restrict__ slice =
        reinterpret_cast<const float4*>(xf) + (size_t)oct * n_nodes * 2;

    const int j  = threadIdx.x & 1;
    const int pr = threadIdx.x >> 1;

    float acc = 0.0f;
    const long long estep = (long long)nb * 128;
    long long e = (long long)obid * 128 + pr;
    #pragma unroll 2
    for (; e < nnz; e += estep) {
        const int r   = __builtin_nontemporal_load(rows + e);
        const int c   = __builtin_nontemporal_load(cols + e);
        const float v = __builtin_nontemporal_load(vals + e);
        const float4 af = slice[(size_t)r * 2 + j];
        const float4 bf = slice[(size_t)c * 2 + j];
        acc += v * dot16_h(af, bf);
    }
    block_reduce_store(acc, partials);
}

// fp32 last-resort fallback (tiny workspace)
__global__ __launch_bounds__(256) void edge_dot_f_kernel(
    const float* __restrict__ x,
    const int* __restrict__ rows,
    const int* __restrict__ cols,
    const float* __restrict__ vals,
    float* __restrict__ partials,
    int nnz)
{
    const float4* __restrict__ x4 = reinterpret_cast<const float4*>(x);
    const int sub = threadIdx.x & 31;
    const int groupInBlock = threadIdx.x >> 5;
    const int groupsPerBlock = blockDim.x >> 5;
    const long long gstride = (long long)gridDim.x * groupsPerBlock;
    long long e = (long long)blockIdx.x * groupsPerBlock + groupInBlock;

    float acc = 0.0f;
    for (; e < nnz; e += gstride) {
        const int r = rows[e];
        const int c = cols[e];
        const float v = vals[e];
        const float4 a = x4[(size_t)r * 32 + sub];
        const float4 b = x4[(size_t)c * 32 + sub];
        acc += v * (a.x * b.x + a.y * b.y + a.z * b.z + a.w * b.w);
    }
    block_reduce_store(acc, partials);
}

__global__ __launch_bounds__(1024) void final_reduce_kernel(
    const float* __restrict__ partials, int n,
    float* __restrict__ out, float inv_nnz)
{
    float acc = 0.0f;
    for (int i = threadIdx.x; i < n; i += blockDim.x)
        acc += partials[i];
    #pragma unroll
    for (int m = 1; m < 64; m <<= 1)
        acc += __shfl_xor(acc, m);

    __shared__ float lds[16];
    const int lane = threadIdx.x & 63;
    const int wid  = threadIdx.x >> 6;
    if (lane == 0) lds[wid] = acc;
    __syncthreads();
    if (threadIdx.x == 0) {
        float s = 0.0f;
        const int nw = blockDim.x >> 6;
        for (int w = 0; w < nw; ++w) s += lds[w];
        out[0] = s * inv_nnz;
    }
}

extern "C" void kernel_launch(void* const* d_in, const int* in_sizes, int n_in,
                              void* d_out, int out_size, void* d_ws, size_t ws_size,
                              hipStream_t stream) {
    const float* x    = (const float*)d_in[0];
    const int*   rows = (const int*)d_in[1];
    const int*   cols = (const int*)d_in[2];
    const float* vals = (const float*)d_in[3];
    const int nnz = in_sizes[1];
    const int nfeat_total = in_sizes[0];        // n_nodes * 128
    const int n_nodes = nfeat_total / 128;

    const int GRID = 2048;                      // multiple of 8; 8 waves/SIMD
    const float inv_nnz = 1.0f / (float)nnz;

    size_t xf_b = ((size_t)nfeat_total * 2 + 255) & ~(size_t)255;
    size_t pk_b = ((size_t)nnz * 8 + 255) & ~(size_t)255;
    size_t part_b = (size_t)GRID * sizeof(float);

    const bool can_slice =
        (n_nodes <= 131072) && ((size_t)n_nodes * 128 == (size_t)nfeat_total);

    if (can_slice && ws_size >= xf_b + pk_b + part_b) {
        __half* xf = (__half*)d_ws;
        unsigned long long* packed =
            (unsigned long long*)((char*)d_ws + xf_b);
        float* partials = (float*)((char*)d_ws + xf_b + pk_b);

        slice_f2h_kernel<<<(n_nodes + 255) / 256, 256, 0, stream>>>(x, xf, n_nodes);
        pack_edges_kernel<<<2048, 256, 0, stream>>>(rows, cols, vals, packed, nnz);
        edge_dot_slice_packed<<<GRID, 256, 0, stream>>>(xf, packed, partials,
                                                        nnz, n_nodes);
        final_reduce_kernel<<<1, 1024, 0, stream>>>(partials, GRID,
                                                    (float*)d_out, inv_nnz);
    } else if (can_slice && ws_size >= xf_b + part_b) {
        __half* xf = (__half*)d_ws;
        float* partials = (float*)((char*)d_ws + xf_b);

        slice_f2h_kernel<<<(n_nodes + 255) / 256, 256, 0, stream>>>(x, xf, n_nodes);
        edge_dot_slice_raw<<<GRID, 256, 0, stream>>>(xf, rows, cols, vals,
                                                     partials, nnz, n_nodes);
        final_reduce_kernel<<<1, 1024, 0, stream>>>(partials, GRID,
                                                    (float*)d_out, inv_nnz);
    } else {
        float* partials = (float*)d_ws;
        int g = GRID;
        if ((size_t)g * sizeof(float) > ws_size) g = (int)(ws_size / sizeof(float));
        const int maxGroups = (nnz + 7) / 8;
        if (g > maxGroups) g = maxGroups;
        if (g < 1) g = 1;
        edge_dot_f_kernel<<<g, 256, 0, stream>>>(x, rows, cols, vals, partials, nnz);
        final_reduce_kernel<<<1, 1024, 0, stream>>>(partials, g,
                                                    (float*)d_out, inv_nnz);
    }
}

// Round 5
// 166.714 us; speedup vs baseline: 1.0628x; 1.0628x over previous
//
#include <hip/hip_runtime.h>
#include <hip/hip_fp16.h>

// bias = (1/nnz) * sum_e vals[e] * dot(x[rows[e]], x[cols[e]])
// N_FEAT = 128.
//
// Round-5: same feature-sliced layout as round 4 (xf[8][n][16] fp16, each
// 3.2MB slice resident in one XCD's 4MB L2; 8B packed edge records), but the
// gather loop is restructured for deep MLP: U=8 edges per lane-pair with
// phase-separated loads (all packed -> all gathers -> all math), ~24
// outstanding VMEM per wave instead of ~3. Round-4 showed FETCH=62MB (slices
// resident) but only ~9 L2 req/clk/XCD with VGPR=24 => latency-bound.

#define UNROLL_E 8

union Pack32 { __half2 h2[8]; float4 f4[2]; };

// x [n][128] f32  ->  xf [8][n][16] f16
__global__ __launch_bounds__(256) void slice_f2h_kernel(
    const float* __restrict__ x, __half* __restrict__ xf, int n_nodes)
{
    int n = blockIdx.x * blockDim.x + threadIdx.x;
    const int stride = gridDim.x * blockDim.x;
    for (; n < n_nodes; n += stride) {
        const float4* xr = reinterpret_cast<const float4*>(x + (size_t)n * 128);
        #pragma unroll
        for (int k = 0; k < 8; ++k) {
            const float4 f0 = xr[k * 4 + 0];
            const float4 f1 = xr[k * 4 + 1];
            const float4 f2 = xr[k * 4 + 2];
            const float4 f3 = xr[k * 4 + 3];
            Pack32 p;
            p.h2[0] = __floats2half2_rn(f0.x, f0.y);
            p.h2[1] = __floats2half2_rn(f0.z, f0.w);
            p.h2[2] = __floats2half2_rn(f1.x, f1.y);
            p.h2[3] = __floats2half2_rn(f1.z, f1.w);
            p.h2[4] = __floats2half2_rn(f2.x, f2.y);
            p.h2[5] = __floats2half2_rn(f2.z, f2.w);
            p.h2[6] = __floats2half2_rn(f3.x, f3.y);
            p.h2[7] = __floats2half2_rn(f3.z, f3.w);
            float4* dst = reinterpret_cast<float4*>(
                xf + ((size_t)k * n_nodes + n) * 16);
            dst[0] = p.f4[0];
            dst[1] = p.f4[1];
        }
    }
}

// (row, col, val) -> 8B record: row[0:17) | col[17:34) | half(val)[34:50)
__global__ __launch_bounds__(256) void pack_edges_kernel(
    const int* __restrict__ rows, const int* __restrict__ cols,
    const float* __restrict__ vals,
    unsigned long long* __restrict__ packed, int nnz)
{
    int e = blockIdx.x * blockDim.x + threadIdx.x;
    const int stride = gridDim.x * blockDim.x;
    for (; e < nnz; e += stride) {
        const unsigned long long r = (unsigned)rows[e];
        const unsigned long long c = (unsigned)cols[e];
        const __half hv = __float2half_rn(vals[e]);
        const unsigned long long hb =
            (unsigned long long)*reinterpret_cast<const unsigned short*>(&hv);
        packed[e] = r | (c << 17) | (hb << 34);
    }
}

__device__ __forceinline__ float dot16_h(const float4& af, const float4& bf)
{
    const __half2* a2 = reinterpret_cast<const __half2*>(&af);
    const __half2* b2 = reinterpret_cast<const __half2*>(&bf);
    float d = 0.0f;
    #pragma unroll
    for (int k = 0; k < 4; ++k) {
        const float2 fa = __half22float2(a2[k]);
        const float2 fb = __half22float2(b2[k]);
        d += fa.x * fb.x + fa.y * fb.y;
    }
    return d;
}

__device__ __forceinline__ void block_reduce_store(
    float acc, float* __restrict__ partials)
{
    #pragma unroll
    for (int m = 1; m < 64; m <<= 1)
        acc += __shfl_xor(acc, m);
    __shared__ float s_red[4];
    const int lane = threadIdx.x & 63;
    const int wid  = threadIdx.x >> 6;
    if (lane == 0) s_red[wid] = acc;
    __syncthreads();
    if (threadIdx.x == 0)
        partials[blockIdx.x] = s_red[0] + s_red[1] + s_red[2] + s_red[3];
}

// deep-MLP gather: 2 lanes/edge (32B coalesced per node), U edges in flight
__global__ __launch_bounds__(256, 4) void edge_dot_slice_mlp(
    const __half* __restrict__ xf,
    const unsigned long long* __restrict__ packed,
    float* __restrict__ partials, int nnz, int n_nodes)
{
    const int oct  = blockIdx.x & 7;     // XCD / feature-slice id
    const int obid = blockIdx.x >> 3;
    const int nb   = gridDim.x >> 3;
    const float4* __restrict__ slice =
        reinterpret_cast<const float4*>(xf) + (size_t)oct * n_nodes * 2;

    const int j  = threadIdx.x & 1;      // which 16B half of the 32B slice-row
    const int pr = threadIdx.x >> 1;     // pair index within block (0..127)

    float acc0 = 0.0f, acc1 = 0.0f;
    const long long tile  = 128LL * UNROLL_E;          // edges per block-tile
    const long long tstep = (long long)nb * tile;

    for (long long b = (long long)obid * tile + pr; b < nnz; b += tstep) {
        // Phase A: issue all packed loads
        unsigned long long rec[UNROLL_E];
        #pragma unroll
        for (int k = 0; k < UNROLL_E; ++k) {
            const long long e = b + (long long)k * 128;
            rec[k] = (e < nnz) ? __builtin_nontemporal_load(packed + e) : 0ull;
        }
        // Phase B: decode + issue all gathers
        float4 af[UNROLL_E], bf[UNROLL_E];
        float  vv[UNROLL_E];
        #pragma unroll
        for (int k = 0; k < UNROLL_E; ++k) {
            const int r = (int)(rec[k] & 0x1FFFF);
            const int c = (int)((rec[k] >> 17) & 0x1FFFF);
            const unsigned short hb = (unsigned short)(rec[k] >> 34);
            vv[k] = __half2float(*reinterpret_cast<const __half*>(&hb));
            af[k] = slice[(size_t)r * 2 + j];
            bf[k] = slice[(size_t)c * 2 + j];
        }
        // Phase C: math (two acc chains)
        #pragma unroll
        for (int k = 0; k < UNROLL_E; k += 2) {
            acc0 += vv[k]     * dot16_h(af[k],     bf[k]);
            acc1 += vv[k + 1] * dot16_h(af[k + 1], bf[k + 1]);
        }
    }
    block_reduce_store(acc0 + acc1, partials);
}

// variant without the packed array (smaller workspace): reads raw edge lists
__global__ __launch_bounds__(256) void edge_dot_slice_raw(
    const __half* __restrict__ xf,
    const int* __restrict__ rows, const int* __restrict__ cols,
    const float* __restrict__ vals,
    float* __restrict__ partials, int nnz, int n_nodes)
{
    const int oct  = blockIdx.x & 7;
    const int obid = blockIdx.x >> 3;
    const int nb   = gridDim.x >> 3;
    const float4* __restrict__ slice =
        reinterpret_cast<const float4*>(xf) + (size_t)oct * n_nodes * 2;

    const int j  = threadIdx.x & 1;
    const int pr = threadIdx.x >> 1;

    float acc = 0.0f;
    const long long estep = (long long)nb * 128;
    long long e = (long long)obid * 128 + pr;
    #pragma unroll 2
    for (; e < nnz; e += estep) {
        const int r   = __builtin_nontemporal_load(rows + e);
        const int c   = __builtin_nontemporal_load(cols + e);
        const float v = __builtin_nontemporal_load(vals + e);
        const float4 af = slice[(size_t)r * 2 + j];
        const float4 bf = slice[(size_t)c * 2 + j];
        acc += v * dot16_h(af, bf);
    }
    block_reduce_store(acc, partials);
}

// fp32 last-resort fallback (tiny workspace)
__global__ __launch_bounds__(256) void edge_dot_f_kernel(
    const float* __restrict__ x,
    const int* __restrict__ rows,
    const int* __restrict__ cols,
    const float* __restrict__ vals,
    float* __restrict__ partials,
    int nnz)
{
    const float4* __restrict__ x4 = reinterpret_cast<const float4*>(x);
    const int sub = threadIdx.x & 31;
    const int groupInBlock = threadIdx.x >> 5;
    const int groupsPerBlock = blockDim.x >> 5;
    const long long gstride = (long long)gridDim.x * groupsPerBlock;
    long long e = (long long)blockIdx.x * groupsPerBlock + groupInBlock;

    float acc = 0.0f;
    for (; e < nnz; e += gstride) {
        const int r = rows[e];
        const int c = cols[e];
        const float v = vals[e];
        const float4 a = x4[(size_t)r * 32 + sub];
        const float4 b = x4[(size_t)c * 32 + sub];
        acc += v * (a.x * b.x + a.y * b.y + a.z * b.z + a.w * b.w);
    }
    block_reduce_store(acc, partials);
}

__global__ __launch_bounds__(1024) void final_reduce_kernel(
    const float* __restrict__ partials, int n,
    float* __restrict__ out, float inv_nnz)
{
    float acc = 0.0f;
    for (int i = threadIdx.x; i < n; i += blockDim.x)
        acc += partials[i];
    #pragma unroll
    for (int m = 1; m < 64; m <<= 1)
        acc += __shfl_xor(acc, m);

    __shared__ float lds[16];
    const int lane = threadIdx.x & 63;
    const int wid  = threadIdx.x >> 6;
    if (lane == 0) lds[wid] = acc;
    __syncthreads();
    if (threadIdx.x == 0) {
        float s = 0.0f;
        const int nw = blockDim.x >> 6;
        for (int w = 0; w < nw; ++w) s += lds[w];
        out[0] = s * inv_nnz;
    }
}

extern "C" void kernel_launch(void* const* d_in, const int* in_sizes, int n_in,
                              void* d_out, int out_size, void* d_ws, size_t ws_size,
                              hipStream_t stream) {
    const float* x    = (const float*)d_in[0];
    const int*   rows = (const int*)d_in[1];
    const int*   cols = (const int*)d_in[2];
    const float* vals = (const float*)d_in[3];
    const int nnz = in_sizes[1];
    const int nfeat_total = in_sizes[0];        // n_nodes * 128
    const int n_nodes = nfeat_total / 128;

    const int GRID = 2048;                      // multiple of 8
    const float inv_nnz = 1.0f / (float)nnz;

    size_t xf_b = ((size_t)nfeat_total * 2 + 255) & ~(size_t)255;
    size_t pk_b = ((size_t)nnz * 8 + 255) & ~(size_t)255;
    size_t part_b = (size_t)GRID * sizeof(float);

    const bool can_slice =
        (n_nodes <= 131072) && ((size_t)n_nodes * 128 == (size_t)nfeat_total);

    if (can_slice && ws_size >= xf_b + pk_b + part_b) {
        __half* xf = (__half*)d_ws;
        unsigned long long* packed =
            (unsigned long long*)((char*)d_ws + xf_b);
        float* partials = (float*)((char*)d_ws + xf_b + pk_b);

        slice_f2h_kernel<<<(n_nodes + 255) / 256, 256, 0, stream>>>(x, xf, n_nodes);
        pack_edges_kernel<<<2048, 256, 0, stream>>>(rows, cols, vals, packed, nnz);
        edge_dot_slice_mlp<<<GRID, 256, 0, stream>>>(xf, packed, partials,
                                                     nnz, n_nodes);
        final_reduce_kernel<<<1, 1024, 0, stream>>>(partials, GRID,
                                                    (float*)d_out, inv_nnz);
    } else if (can_slice && ws_size >= xf_b + part_b) {
        __half* xf = (__half*)d_ws;
        float* partials = (float*)((char*)d_ws + xf_b);

        slice_f2h_kernel<<<(n_nodes + 255) / 256, 256, 0, stream>>>(x, xf, n_nodes);
        edge_dot_slice_raw<<<GRID, 256, 0, stream>>>(xf, rows, cols, vals,
                                                     partials, nnz, n_nodes);
        final_reduce_kernel<<<1, 1024, 0, stream>>>(partials, GRID,
                                                    (float*)d_out, inv_nnz);
    } else {
        float* partials = (float*)d_ws;
        int g = GRID;
        if ((size_t)g * sizeof(float) > ws_size) g = (int)(ws_size / sizeof(float));
        const int maxGroups = (nnz + 7) / 8;
        if (g > maxGroups) g = maxGroups;
        if (g < 1) g = 1;
        edge_dot_f_kernel<<<g, 256, 0, stream>>>(x, rows, cols, vals, partials, nnz);
        final_reduce_kernel<<<1, 1024, 0, stream>>>(partials, g,
                                                    (float*)d_out, inv_nnz);
    }
}